// Round 21
// baseline (138.623 us; speedup 1.0000x reference)
//
#include <hip/hip_runtime.h>

// ---------- problem constants ----------
constexpr int T_SEQ = 2048;
constexpr int CDIM  = 768;
constexpr int HEADS = 12;
constexpr int DH    = 64;
constexpr int BATCH = 2;
constexpr int BH_TOT = BATCH * HEADS;   // 24
constexpr int NROWS  = BATCH * T_SEQ;   // 4096
constexpr int JS     = 2;               // j-split in fused_pv (TLP: 1536 blocks = 6/CU)
constexpr float RMS_EPS = 1.1920929e-07f;  // np.finfo(float32).eps
// fold softmax scale into Q: S' = (q*QSCALE). k ; E = 2^(S') = e^(S/8)
constexpr float QSCALE = 0.18033688011112042f;  // 0.125 * log2(e)

// Fragment-ordered tile layout (per bh, per 128-row tile of 8192 shorts):
//  QK rows:  element (rr,d) at chunk c = ((rr>>4)*2 + (d>>5))*64 + ((d>>3)&3)*16 + (rr&15),
//            short idx = c*8 + (d&7).  An MFMA fragment (fixed rb,ks) = chunk base + lane
//            -> contiguous 1KB, coalesced in global AND conflict-free in LDS.
//  V^T:      element (f,jj) at c = (jj>>5)*256 + (f>>4)*64 + ((jj>>3)&3)*16 + (f&15),
//            short idx = c*8 + (jj&7). PV fragment (fixed ks2,ni) = chunk base + lane.
//  Both are j-major at 64-row granularity: a 64-row subtile is a contiguous
//  4096-short half of its 128-row tile.

typedef __attribute__((ext_vector_type(8))) short bf16x8;
typedef __attribute__((ext_vector_type(4))) float f32x4;
typedef __attribute__((ext_vector_type(4))) unsigned int u32x4;

__device__ __forceinline__ unsigned short f2bf(float f) {
    union { float f; unsigned int u; } v; v.f = f;
    unsigned int u = v.u;
    unsigned int r = (u + 0x7fffu + ((u >> 16) & 1u)) >> 16;  // RNE
    return (unsigned short)r;
}
__device__ __forceinline__ float b2f(unsigned short h) {
    union { unsigned int u; float f; } v; v.u = ((unsigned int)h) << 16;
    return v.f;
}
__device__ __forceinline__ unsigned int cvt_pk_bf16(float lo, float hi) {
    unsigned int r;
    asm("v_cvt_pk_bf16_f32 %0, %1, %2" : "=v"(r) : "v"(lo), "v"(hi));
    return r;
}
__device__ __forceinline__ float fast_exp2(float x) {
    float r;
    asm("v_exp_f32 %0, %1" : "=v"(r) : "v"(x));
    return r;
}
__device__ __forceinline__ float fast_rcp(float x) {
    return __builtin_amdgcn_rcpf(x);
}
__device__ __forceinline__ void gld_lds16(const void* g, void* l) {
    __builtin_amdgcn_global_load_lds(
        (const __attribute__((address_space(1))) void*)g,
        (__attribute__((address_space(3))) void*)l, 16, 0, 0);
}
// linear 16KB stage: contiguous global tile -> contiguous LDS (both coalesced)
__device__ __forceinline__ void stageLin(const unsigned short* g, unsigned short* l, int tid) {
#pragma unroll
    for (int p = 0; p < 4; ++p) {
        int d = (p * 256 + tid) * 16;
        gld_lds16((const char*)g + d, (char*)l + d);
    }
}
// linear 8KB stage
__device__ __forceinline__ void stage8k(const unsigned short* g, unsigned short* l, int tid) {
#pragma unroll
    for (int p = 0; p < 2; ++p) {
        int d = (p * 256 + tid) * 16;
        gld_lds16((const char*)g + d, (char*)l + d);
    }
}

// ---------- prep: x, W -> bf16; W^T -> bf16 ----------
__global__ __launch_bounds__(256) void prep_kernel(
    const float* __restrict__ x, const float* __restrict__ W,
    unsigned short* __restrict__ xh,
    unsigned short* __restrict__ Wh, unsigned short* __restrict__ WTh)
{
    const size_t NC = (size_t)NROWS * CDIM;
    const size_t WSZ = (size_t)CDIM * CDIM;
    size_t stride = (size_t)gridDim.x * blockDim.x;
    for (size_t i = (size_t)blockIdx.x * blockDim.x + threadIdx.x; i < NC; i += stride)
        xh[i] = f2bf(x[i]);
    for (size_t i = (size_t)blockIdx.x * blockDim.x + threadIdx.x; i < WSZ; i += stride) {
        unsigned short h = f2bf(W[i]);
        Wh[i] = h;
        size_t k = i / CDIM, c = i % CDIM;
        WTh[c * CDIM + k] = h;
    }
}

// ---------- 64x64-tile NT bf16 MFMA GEMM: C = A * B^T ----------------------
// 1-D grid, XCD-swizzled. Double-buffered staging, one barrier per k-step.
__global__ __launch_bounds__(256) void gemm64_nt(
    const unsigned short* __restrict__ A, const unsigned short* __restrict__ B,
    float* __restrict__ C, int M, int N, int K, int ldc)
{
    __shared__ unsigned short sA[2][64 * 64], sB[2][64 * 64];   // 32 KB
    const int tid = threadIdx.x;
    const int lane = tid & 63;
    const int wv = tid >> 6;
    const int wr = wv >> 1, wc = wv & 1;
    const int li = lane & 15, g = lane >> 4;

    const int nbx = N / 64;
    const int wgid = blockIdx.x;
    const int xcd = wgid & 7;
    const int idx = wgid >> 3;                 // 0 .. total/8-1
    const int perx = (M / 64) / 8;             // row-groups per XCD
    const int my = xcd * perx + idx / nbx;
    const int nx = idx % nbx;
    const int M0 = my * 64, N0 = nx * 64;

    f32x4 acc[2][2];
#pragma unroll
    for (int i = 0; i < 2; ++i)
#pragma unroll
        for (int j = 0; j < 2; ++j) acc[i][j] = (f32x4)0.0f;

    // prologue: stage k0 = 0 into buf 0
#pragma unroll
    for (int p = 0; p < 2; ++p) {
        int dd = tid * 16 + p * 4096;
        int row = dd >> 7;
        int cb = (dd & 127) ^ ((row & 7) << 4);
        gld_lds16((const char*)A + ((size_t)(M0 + row) * K) * 2 + cb, (char*)sA[0] + dd);
        gld_lds16((const char*)B + ((size_t)(N0 + row) * K) * 2 + cb, (char*)sB[0] + dd);
    }

    int buf = 0;
    for (int k0 = 0; k0 < K; k0 += 64) {
        __syncthreads();   // drains the stage targeting buf
        if (k0 + 64 < K) {
#pragma unroll
            for (int p = 0; p < 2; ++p) {
                int dd = tid * 16 + p * 4096;
                int row = dd >> 7;
                int cb = (dd & 127) ^ ((row & 7) << 4);
                gld_lds16((const char*)A + ((size_t)(M0 + row) * K + k0 + 64) * 2 + cb,
                          (char*)sA[buf ^ 1] + dd);
                gld_lds16((const char*)B + ((size_t)(N0 + row) * K + k0 + 64) * 2 + cb,
                          (char*)sB[buf ^ 1] + dd);
            }
        }
#pragma unroll
        for (int ks = 0; ks < 2; ++ks) {
            const int ko = ks * 32 + g * 8;
            bf16x8 a[2], b[2];
#pragma unroll
            for (int mi = 0; mi < 2; ++mi) {
                int r = wr * 32 + mi * 16 + li;
                a[mi] = *(const bf16x8*)((char*)sA[buf] + ((r * 128 + ko * 2) ^ ((r & 7) << 4)));
            }
#pragma unroll
            for (int ni = 0; ni < 2; ++ni) {
                int r = wc * 32 + ni * 16 + li;
                b[ni] = *(const bf16x8*)((char*)sB[buf] + ((r * 128 + ko * 2) ^ ((r & 7) << 4)));
            }
#pragma unroll
            for (int mi = 0; mi < 2; ++mi)
#pragma unroll
                for (int ni = 0; ni < 2; ++ni)
                    acc[mi][ni] = __builtin_amdgcn_mfma_f32_16x16x32_bf16(a[mi], b[ni], acc[mi][ni], 0, 0, 0);
        }
        buf ^= 1;
    }
#pragma unroll
    for (int mi = 0; mi < 2; ++mi)
#pragma unroll
        for (int ni = 0; ni < 2; ++ni)
#pragma unroll
            for (int r = 0; r < 4; ++r) {
                int row = M0 + wr * 32 + mi * 16 + g * 4 + r;
                int col = N0 + wc * 32 + ni * 16 + li;
                C[(size_t)row * ldc + col] = acc[mi][ni][r];
            }
}

// ---------- fused RMSNorm + QKV write; q/k in fragment order ----------
__global__ __launch_bounds__(256) void rmsqkv_kernel(
    const float* __restrict__ wbuf,
    const float* __restrict__ g1, const float* __restrict__ g2, const float* __restrict__ g3,
    unsigned short* __restrict__ qbf, unsigned short* __restrict__ kbf,
    unsigned short* __restrict__ vb)
{
    const int d = threadIdx.x & 63;
    const int wv = threadIdx.x >> 6;
    const int ridx = blockIdx.x * 4 + wv;
    const int bt = ridx / HEADS;
    const int h = ridx % HEADS;
    const int b = bt >> 11, t = bt & (T_SEQ - 1);

    float v = wbuf[(size_t)bt * CDIM + h * DH + d];
    float ss = v * v;
#pragma unroll
    for (int m = 32; m; m >>= 1) ss += __shfl_xor(ss, m);
    float r = rsqrtf(ss * (1.0f / 64.0f) + RMS_EPS);
    float wn = v * r;

    const int bh = b * HEADS + h;
    // fragment-ordered index for (t, d)
    size_t fidx = (size_t)bh * (T_SEQ * DH)
                + (size_t)(t >> 7) * 8192
                + (size_t)((((t & 127) >> 4) * 2 + (d >> 5)) * 512
                           + ((d >> 3) & 3) * 128 + (t & 15) * 8 + (d & 7));
    qbf[fidx] = f2bf(wn * g1[d] * QSCALE);
    kbf[fidx] = f2bf(wn * g2[d]);
    vb[((size_t)bh * T_SEQ + t) * DH + d] = f2bf(wn * g3[d]);
}

// ---------- v [bh][t][f] -> fragment-ordered V^T tiles ----------
__global__ __launch_bounds__(256) void vtrans_kernel(
    const unsigned short* __restrict__ vb, unsigned short* __restrict__ vTf)
{
    __shared__ unsigned short raw[128 * 72];   // row stride 72 shorts (144B, 16B-aligned)
    const int bh = blockIdx.y, jt = blockIdx.x;
    const int tid = threadIdx.x;
    const unsigned short* src = &vb[((size_t)bh * T_SEQ + jt * 128) * DH];
#pragma unroll
    for (int p = 0; p < 4; ++p) {
        int i16 = p * 256 + tid;
        int r = i16 >> 3, c8 = i16 & 7;
        *(u32x4*)&raw[r * 72 + c8 * 8] = *(const u32x4*)&src[r * 64 + c8 * 8];
    }
    __syncthreads();
    unsigned short* dst = &vTf[(size_t)bh * (T_SEQ * DH) + (size_t)jt * 8192];
#pragma unroll
    for (int p = 0; p < 4; ++p) {
        int c = p * 256 + tid;
        int li = c & 15, g = (c >> 4) & 3, ni = (c >> 6) & 3, ks2 = c >> 8;
        int f = ni * 16 + li;
        int j0 = ks2 * 32 + g * 8;
        u32x4 out;
#pragma unroll
        for (int k = 0; k < 4; ++k) {
            unsigned int lo = raw[(j0 + 2 * k) * 72 + f];
            unsigned int hi = raw[(j0 + 2 * k + 1) * 72 + f];
            out[k] = lo | (hi << 16);
        }
        *(u32x4*)&dst[c * 8] = out;
    }
}

// ---------- pass 1: row/col sums of E = 2^(Q'K^T) --------------------------
// 1-D grid 1536, XCD-swizzled: each XCD owns 3 whole bh (Q/K panels resident).
// Wave w owns j rows w*32..+32 (K frags in regs). sQ double-buffered linear.
__global__ __launch_bounds__(256) void sums_kernel(
    const unsigned short* __restrict__ qbf, const unsigned short* __restrict__ kbf,
    float* __restrict__ rowsum, float* __restrict__ colsum)
{
    __shared__ unsigned short sQ[2][8192];
    const int tid = threadIdx.x;
    const int lane = tid & 63;
    const int w = tid >> 6;
    const int li = lane & 15;
    const int g = lane >> 4;

    const int wgid = blockIdx.x;
    const int xcd = wgid & 7;
    const int idx = wgid >> 3;                  // 0..191
    const int bh = xcd * 3 + (idx >> 6);        // 24 bh, 3 per XCD
    const int w2 = idx & 63;
    const int jx = w2 & 15;                     // 16 j-tiles
    const int iy = w2 >> 4;                     // 4 i-chunks
    const int J0 = jx * 128;

    const unsigned short* ktile = kbf + (size_t)bh * (T_SEQ * DH) + (size_t)jx * 8192;
    bf16x8 kf[2][2];
#pragma unroll
    for (int jb = 0; jb < 2; ++jb)
#pragma unroll
        for (int ks = 0; ks < 2; ++ks)
            kf[jb][ks] = *(const bf16x8*)&ktile[(size_t)((((w * 2 + jb) * 2 + ks) * 64 + lane) * 8)];

    const unsigned short* qbase = qbf + (size_t)bh * (T_SEQ * DH) + (size_t)(iy * 4) * 8192;
    stageLin(qbase, sQ[0], tid);
    __syncthreads();

    float csum[2][4];
#pragma unroll
    for (int jb = 0; jb < 2; ++jb)
#pragma unroll
        for (int r = 0; r < 4; ++r) csum[jb][r] = 0.0f;

    for (int it = 0; it < 4; ++it) {
        const int I0 = iy * 512 + it * 128;
        if (it + 1 < 4)
            stageLin(qbase + (size_t)(it + 1) * 8192, sQ[(it + 1) & 1], tid);
        const unsigned short* q = sQ[it & 1];

#pragma unroll
        for (int half = 0; half < 2; ++half) {
            f32x4 acc[2][4];
#pragma unroll
            for (int jb = 0; jb < 2; ++jb)
#pragma unroll
                for (int ib = 0; ib < 4; ++ib) acc[jb][ib] = (f32x4)0.0f;
#pragma unroll
            for (int ks = 0; ks < 2; ++ks) {
#pragma unroll
                for (int ib = 0; ib < 4; ++ib) {
                    bf16x8 qf = *(const bf16x8*)&q[(((half * 4 + ib) * 2 + ks) * 64 + lane) * 8];
#pragma unroll
                    for (int jb = 0; jb < 2; ++jb)
                        acc[jb][ib] = __builtin_amdgcn_mfma_f32_16x16x32_bf16(kf[jb][ks], qf, acc[jb][ib], 0, 0, 0);
                }
            }
#pragma unroll
            for (int ib = 0; ib < 4; ++ib) {
                float rp = 0.0f;
#pragma unroll
                for (int jb = 0; jb < 2; ++jb)
#pragma unroll
                    for (int r = 0; r < 4; ++r) {
                        float e = fast_exp2(acc[jb][ib][r]);
                        csum[jb][r] += e;
                        rp += e;
                    }
                rp += __shfl_xor(rp, 16);
                rp += __shfl_xor(rp, 32);      // sum over this wave's 32 j
                if (g == 0)
                    atomicAdd(&rowsum[(size_t)bh * T_SEQ + I0 + half * 64 + ib * 16 + li], rp);
            }
        }
        __syncthreads();   // drains next-tile stage (hidden under compute)
    }
#pragma unroll
    for (int jb = 0; jb < 2; ++jb)
#pragma unroll
        for (int r = 0; r < 4; ++r) {
            float c = csum[jb][r];
            c += __shfl_xor(c, 1); c += __shfl_xor(c, 2);
            c += __shfl_xor(c, 4); c += __shfl_xor(c, 8);
            if (li == 0)
                atomicAdd(&colsum[(size_t)bh * T_SEQ + J0 + w * 32 + jb * 16 + g * 4 + r], c);
        }
}

// ---------- in-place reciprocal over rowsum||colsum (vectorized) ----------
__global__ __launch_bounds__(256) void inv_kernel(float* __restrict__ s, int n4)
{
    int i = blockIdx.x * 256 + threadIdx.x;
    if (i < n4) {
        f32x4 v = ((f32x4*)s)[i];
        v[0] = fast_rcp(v[0]); v[1] = fast_rcp(v[1]);
        v[2] = fast_rcp(v[2]); v[3] = fast_rcp(v[3]);
        ((f32x4*)s)[i] = v;
    }
}

// ---------- pass 2: swapped QK^T + scale + PV; KVBLK=64, js=2 --------------
// 1-D grid 1536 = 6 blocks/CU (LDS cap) -> 24 waves/CU TLP. Each XCD owns 6
// (bh,jc) groups. Per block: 16 j-tiles, T14 2-barrier schedule, f32 partial.
__global__ __launch_bounds__(256) void fused_pv_kernel(
    const unsigned short* __restrict__ qbf, const unsigned short* __restrict__ kbf,
    const unsigned short* __restrict__ vTf,
    const float* __restrict__ rowinv, const float* __restrict__ colinv,
    float* __restrict__ ypart)
{
    __shared__ unsigned short sK[4096];      // 8 KB (64 j-rows)
    __shared__ unsigned short sV[4096];      // 8 KB
    __shared__ unsigned short sP[4096];      // 8 KB; 2KB wave-private regions

    const int tid = threadIdx.x;
    const int lane = tid & 63;
    const int w = tid >> 6;
    const int li = lane & 15;
    const int g = lane >> 4;

    const int wgid = blockIdx.x;
    const int xcd = wgid & 7;
    const int idx = wgid >> 3;                 // 0..191
    const int grp = xcd * 6 + (idx >> 5);      // 48 (bh,jc) groups, 6 per XCD
    const int it  = idx & 31;                  // 32 i-tiles
    const int bh = grp >> 1;
    const int jc = grp & 1;
    const int I0 = it * 64;
    const int J0 = jc * (T_SEQ / JS);          // 0 or 1024
    constexpr int NT = T_SEQ / JS / 64;        // 16

    // Q fragments (coalesced 1KB wave loads from fragment-ordered global)
    const int rbq = ((I0 & 127) >> 4) + w;
    const unsigned short* qtile = qbf + (size_t)bh * (T_SEQ * DH) + (size_t)(I0 >> 7) * 8192;
    bf16x8 qf[2];
#pragma unroll
    for (int ks = 0; ks < 2; ++ks)
        qf[ks] = *(const bf16x8*)&qtile[(size_t)(((rbq * 2 + ks) * 64 + lane) * 8)];
    const float rv = rowinv[bh * T_SEQ + I0 + w * 16 + li];

    char* const sPw = (char*)sP + w * 2048;   // this wave's 2KB P region

    f32x4 accy[4];
#pragma unroll
    for (int i = 0; i < 4; ++i) accy[i] = (f32x4)0.0f;

    const size_t bhbase = (size_t)bh * (T_SEQ * DH);
    const unsigned short* kt0 = kbf + bhbase + (size_t)(J0 >> 6) * 4096;  // 64-j subtiles
    const unsigned short* vt0 = vTf + bhbase + (size_t)(J0 >> 6) * 4096;

    // prologue: stage K(0), V(0)
    stage8k(kt0, sK, tid);
    stage8k(vt0, sV, tid);
    __syncthreads();

    for (int jt = 0; jt < NT; ++jt) {
        // --- QK^T (swapped: rows = j, cols = i) from sK ---
        f32x4 accs[4];
#pragma unroll
        for (int jb = 0; jb < 4; ++jb) accs[jb] = (f32x4)0.0f;
#pragma unroll
        for (int ks = 0; ks < 2; ++ks) {
#pragma unroll
            for (int jb = 0; jb < 4; ++jb) {
                bf16x8 kfr = *(const bf16x8*)&sK[((jb * 2 + ks) * 64 + lane) * 8];
                accs[jb] = __builtin_amdgcn_mfma_f32_16x16x32_bf16(kfr, qf[ks], accs[jb], 0, 0, 0);
            }
        }

        // --- pack: P = 2^S' * (rinv_i + cinv_j) -> bf16 -> sP (own region) ---
#pragma unroll
        for (int jb = 0; jb < 4; ++jb) {
            f32x4 cv = *(const f32x4*)&colinv[(size_t)bh * T_SEQ + J0 + jt * 64 + jb * 16 + g * 4];
            float p0 = fast_exp2(accs[jb][0]) * (rv + cv[0]);
            float p1 = fast_exp2(accs[jb][1]) * (rv + cv[1]);
            float p2 = fast_exp2(accs[jb][2]) * (rv + cv[2]);
            float p3 = fast_exp2(accs[jb][3]) * (rv + cv[3]);
            uint2 pw;
            pw.x = cvt_pk_bf16(p0, p1);
            pw.y = cvt_pk_bf16(p2, p3);
            int off = ((jb >> 1) * 4 + (jb & 1) * 2 + (g >> 1)) * 256 + li * 16 + (g & 1) * 8;
            *(uint2*)(sPw + off) = pw;
        }

        __syncthreads();   // (a): sK reads done; drains V(jt) stage from prev (b)
        if (jt + 1 < NT)
            stage8k(kt0 + (size_t)(jt + 1) * 4096, sK, tid);

        // --- PV: y[i][f] += P[i][j] * V^T[f][j] from sP / sV ---
#pragma unroll
        for (int ks2 = 0; ks2 < 2; ++ks2) {
            bf16x8 pf = *(const bf16x8*)(sPw + ((ks2 * 4 + g) * 256 + li * 16));
#pragma unroll
            for (int ni = 0; ni < 4; ++ni) {
                bf16x8 vf = *(const bf16x8*)&sV[(ks2 * 256 + ni * 64 + lane) * 8];
                accy[ni] = __builtin_amdgcn_mfma_f32_16x16x32_bf16(pf, vf, accy[ni], 0, 0, 0);
            }
        }

        __syncthreads();   // (b): sV reads done; drains K(jt+1) stage
        if (jt + 1 < NT)
            stage8k(vt0 + (size_t)(jt + 1) * 4096, sV, tid);
    }

    // store f32 partial: ypart[jc][bh][i][f]
#pragma unroll
    for (int ni = 0; ni < 4; ++ni)
#pragma unroll
        for (int r = 0; r < 4; ++r) {
            int i = I0 + w * 16 + g * 4 + r;
            int f = ni * 16 + li;
            ypart[(((size_t)jc * BH_TOT + bh) * T_SEQ + i) * DH + f] = accy[ni][r];
        }
}

// ---------- reduce JS partials -> bf16 y ----------
__global__ __launch_bounds__(256) void reduce_kernel(
    const float* __restrict__ ypart, unsigned short* __restrict__ yh)
{
    const size_t STR = (size_t)BH_TOT * T_SEQ * DH;
    size_t idx = (size_t)blockIdx.x * 256 + threadIdx.x;   // one per 4 elems
    if (idx >= STR / 4) return;
    f32x4 a = *(const f32x4*)&ypart[idx * 4];
    f32x4 b = *(const f32x4*)&ypart[STR + idx * 4];
    int e = (int)(idx * 4);
    int f = e & 63;
    int rrow = e >> 6;
    int t = rrow & (T_SEQ - 1);
    int bh = rrow >> 11;
    int b_ = bh / HEADS, h = bh % HEADS;
    size_t o = ((size_t)b_ * T_SEQ + t) * CDIM + h * DH + f;
#pragma unroll
    for (int q = 0; q < 4; ++q)
        yh[o + q] = f2bf(a[q] + b[q]);
}

// ---------- host ----------
extern "C" void kernel_launch(void* const* d_in, const int* in_sizes, int n_in,
                              void* d_out, int out_size, void* d_ws, size_t ws_size,
                              hipStream_t stream)
{
    const float* x  = (const float*)d_in[0];
    const float* W  = (const float*)d_in[1];
    const float* g1 = (const float*)d_in[2];
    const float* g2 = (const float*)d_in[3];
    const float* g3 = (const float*)d_in[4];
    float* out = (float*)d_out;

    char* p = (char*)d_ws;
    auto alloc = [&](size_t bytes) -> void* {
        void* r = (void*)p;
        p += (bytes + 255) & ~(size_t)255;
        return r;
    };
    const size_t NC  = (size_t)NROWS * CDIM;
    const size_t WSZ = (size_t)CDIM * CDIM;
    const size_t QSZ = (size_t)BH_TOT * T_SEQ * DH;

    unsigned short* xh   = (unsigned short*)alloc(NC * 2);
    unsigned short* Wh   = (unsigned short*)alloc(WSZ * 2);
    unsigned short* WTh  = (unsigned short*)alloc(WSZ * 2);
    float*          wbuf = (float*)alloc(NC * 4);
    unsigned short* qbf  = (unsigned short*)alloc(QSZ * 2);
    unsigned short* kbf  = (unsigned short*)alloc(QSZ * 2);
    unsigned short* vb   = (unsigned short*)alloc(QSZ * 2);
    unsigned short* vTf  = (unsigned short*)alloc(QSZ * 2);
    unsigned short* yh   = (unsigned short*)alloc(NC * 2);
    float* ypart  = (float*)alloc((size_t)JS * QSZ * 4);
    // rowsum || colsum contiguous: one memset + one in-place inv cover both
    float* rowsum = (float*)alloc((size_t)BH_TOT * T_SEQ * 4 * 2);
    float* colsum = rowsum + (size_t)BH_TOT * T_SEQ;

    prep_kernel<<<2048, 256, 0, stream>>>(x, W, xh, Wh, WTh);
    gemm64_nt<<<(NROWS / 64) * (CDIM / 64), 256, 0, stream>>>(
        xh, Wh, wbuf, NROWS, CDIM, CDIM, CDIM);
    rmsqkv_kernel<<<(NROWS * HEADS) / 4, 256, 0, stream>>>(
        wbuf, g1, g2, g3, qbf, kbf, vb);
    vtrans_kernel<<<dim3(T_SEQ / 128, BH_TOT), 256, 0, stream>>>(vb, vTf);

    hipMemsetAsync(rowsum, 0, (size_t)BH_TOT * T_SEQ * 4 * 2, stream);
    sums_kernel<<<(T_SEQ / 128) * 4 * BH_TOT, 256, 0, stream>>>(
        qbf, kbf, rowsum, colsum);
    {
        int n4 = BH_TOT * T_SEQ * 2 / 4;
        inv_kernel<<<(n4 + 255) / 256, 256, 0, stream>>>(rowsum, n4);
    }

    fused_pv_kernel<<<(T_SEQ / 64) * JS * BH_TOT, 256, 0, stream>>>(
        qbf, kbf, vTf, rowsum, colsum, ypart);
    {
        size_t n4 = (size_t)BH_TOT * T_SEQ * DH / 4;
        reduce_kernel<<<(unsigned)((n4 + 255) / 256), 256, 0, stream>>>(ypart, yh);
    }

    gemm64_nt<<<(NROWS / 64) * (CDIM / 64), 256, 0, stream>>>(
        yh, WTh, out, NROWS, CDIM, CDIM, CDIM);
}

// Round 22
// 131.338 us; speedup vs baseline: 1.0555x; 1.0555x over previous
//
#include <hip/hip_runtime.h>

// ---------- problem constants ----------
constexpr int T_SEQ = 2048;
constexpr int CDIM  = 768;
constexpr int HEADS = 12;
constexpr int DH    = 64;
constexpr int BATCH = 2;
constexpr int BH_TOT = BATCH * HEADS;   // 24
constexpr int NROWS  = BATCH * T_SEQ;   // 4096
constexpr float RMS_EPS = 1.1920929e-07f;  // np.finfo(float32).eps
// fold softmax scale into Q: S' = (q*QSCALE). k ; E = 2^(S') = e^(S/8)
constexpr float QSCALE = 0.18033688011112042f;  // 0.125 * log2(e)

// Fragment-ordered tile layout (per bh, per 128-row tile of 8192 shorts):
//  QK rows:  element (rr,d) at chunk c = ((rr>>4)*2 + (d>>5))*64 + ((d>>3)&3)*16 + (rr&15),
//            short idx = c*8 + (d&7).  An MFMA fragment (fixed rb,ks) = chunk base + lane
//            -> contiguous 1KB, coalesced in global AND conflict-free in LDS.
//  V^T:      element (f,jj) at c = (jj>>5)*256 + (f>>4)*64 + ((jj>>3)&3)*16 + (f&15),
//            short idx = c*8 + (jj&7). PV fragment (fixed ks2,ni) = chunk base + lane.
//  Both are j-major at 64-row granularity: a 64-row subtile is a contiguous
//  4096-short half of its 128-row tile.

typedef __attribute__((ext_vector_type(8))) short bf16x8;
typedef __attribute__((ext_vector_type(4))) float f32x4;
typedef __attribute__((ext_vector_type(4))) unsigned int u32x4;

__device__ __forceinline__ unsigned short f2bf(float f) {
    union { float f; unsigned int u; } v; v.f = f;
    unsigned int u = v.u;
    unsigned int r = (u + 0x7fffu + ((u >> 16) & 1u)) >> 16;  // RNE
    return (unsigned short)r;
}
__device__ __forceinline__ float b2f(unsigned short h) {
    union { unsigned int u; float f; } v; v.u = ((unsigned int)h) << 16;
    return v.f;
}
__device__ __forceinline__ unsigned int cvt_pk_bf16(float lo, float hi) {
    unsigned int r;
    asm("v_cvt_pk_bf16_f32 %0, %1, %2" : "=v"(r) : "v"(lo), "v"(hi));
    return r;
}
__device__ __forceinline__ float fast_exp2(float x) {
    float r;
    asm("v_exp_f32 %0, %1" : "=v"(r) : "v"(x));
    return r;
}
__device__ __forceinline__ float fast_rcp(float x) {
    return __builtin_amdgcn_rcpf(x);
}
__device__ __forceinline__ void gld_lds16(const void* g, void* l) {
    __builtin_amdgcn_global_load_lds(
        (const __attribute__((address_space(1))) void*)g,
        (__attribute__((address_space(3))) void*)l, 16, 0, 0);
}
// linear 16KB stage: contiguous global tile -> contiguous LDS (both coalesced)
__device__ __forceinline__ void stageLin(const unsigned short* g, unsigned short* l, int tid) {
#pragma unroll
    for (int p = 0; p < 4; ++p) {
        int d = (p * 256 + tid) * 16;
        gld_lds16((const char*)g + d, (char*)l + d);
    }
}
// linear 8KB stage
__device__ __forceinline__ void stage8k(const unsigned short* g, unsigned short* l, int tid) {
#pragma unroll
    for (int p = 0; p < 2; ++p) {
        int d = (p * 256 + tid) * 16;
        gld_lds16((const char*)g + d, (char*)l + d);
    }
}

// ---------- prep: x, W -> bf16; W^T -> bf16 ----------
__global__ __launch_bounds__(256) void prep_kernel(
    const float* __restrict__ x, const float* __restrict__ W,
    unsigned short* __restrict__ xh,
    unsigned short* __restrict__ Wh, unsigned short* __restrict__ WTh)
{
    const size_t NC = (size_t)NROWS * CDIM;
    const size_t WSZ = (size_t)CDIM * CDIM;
    size_t stride = (size_t)gridDim.x * blockDim.x;
    for (size_t i = (size_t)blockIdx.x * blockDim.x + threadIdx.x; i < NC; i += stride)
        xh[i] = f2bf(x[i]);
    for (size_t i = (size_t)blockIdx.x * blockDim.x + threadIdx.x; i < WSZ; i += stride) {
        unsigned short h = f2bf(W[i]);
        Wh[i] = h;
        size_t k = i / CDIM, c = i % CDIM;
        WTh[c * CDIM + k] = h;
    }
}

// ---------- 64x64-tile NT bf16 MFMA GEMM: C = A * B^T ----------------------
// 1-D grid, XCD-swizzled. Double-buffered staging, one barrier per k-step.
__global__ __launch_bounds__(256) void gemm64_nt(
    const unsigned short* __restrict__ A, const unsigned short* __restrict__ B,
    float* __restrict__ C, int M, int N, int K, int ldc)
{
    __shared__ unsigned short sA[2][64 * 64], sB[2][64 * 64];   // 32 KB
    const int tid = threadIdx.x;
    const int lane = tid & 63;
    const int wv = tid >> 6;
    const int wr = wv >> 1, wc = wv & 1;
    const int li = lane & 15, g = lane >> 4;

    const int nbx = N / 64;
    const int wgid = blockIdx.x;
    const int xcd = wgid & 7;
    const int idx = wgid >> 3;                 // 0 .. total/8-1
    const int perx = (M / 64) / 8;             // row-groups per XCD
    const int my = xcd * perx + idx / nbx;
    const int nx = idx % nbx;
    const int M0 = my * 64, N0 = nx * 64;

    f32x4 acc[2][2];
#pragma unroll
    for (int i = 0; i < 2; ++i)
#pragma unroll
        for (int j = 0; j < 2; ++j) acc[i][j] = (f32x4)0.0f;

    // prologue: stage k0 = 0 into buf 0
#pragma unroll
    for (int p = 0; p < 2; ++p) {
        int dd = tid * 16 + p * 4096;
        int row = dd >> 7;
        int cb = (dd & 127) ^ ((row & 7) << 4);
        gld_lds16((const char*)A + ((size_t)(M0 + row) * K) * 2 + cb, (char*)sA[0] + dd);
        gld_lds16((const char*)B + ((size_t)(N0 + row) * K) * 2 + cb, (char*)sB[0] + dd);
    }

    int buf = 0;
    for (int k0 = 0; k0 < K; k0 += 64) {
        __syncthreads();   // drains the stage targeting buf
        if (k0 + 64 < K) {
#pragma unroll
            for (int p = 0; p < 2; ++p) {
                int dd = tid * 16 + p * 4096;
                int row = dd >> 7;
                int cb = (dd & 127) ^ ((row & 7) << 4);
                gld_lds16((const char*)A + ((size_t)(M0 + row) * K + k0 + 64) * 2 + cb,
                          (char*)sA[buf ^ 1] + dd);
                gld_lds16((const char*)B + ((size_t)(N0 + row) * K + k0 + 64) * 2 + cb,
                          (char*)sB[buf ^ 1] + dd);
            }
        }
#pragma unroll
        for (int ks = 0; ks < 2; ++ks) {
            const int ko = ks * 32 + g * 8;
            bf16x8 a[2], b[2];
#pragma unroll
            for (int mi = 0; mi < 2; ++mi) {
                int r = wr * 32 + mi * 16 + li;
                a[mi] = *(const bf16x8*)((char*)sA[buf] + ((r * 128 + ko * 2) ^ ((r & 7) << 4)));
            }
#pragma unroll
            for (int ni = 0; ni < 2; ++ni) {
                int r = wc * 32 + ni * 16 + li;
                b[ni] = *(const bf16x8*)((char*)sB[buf] + ((r * 128 + ko * 2) ^ ((r & 7) << 4)));
            }
#pragma unroll
            for (int mi = 0; mi < 2; ++mi)
#pragma unroll
                for (int ni = 0; ni < 2; ++ni)
                    acc[mi][ni] = __builtin_amdgcn_mfma_f32_16x16x32_bf16(a[mi], b[ni], acc[mi][ni], 0, 0, 0);
        }
        buf ^= 1;
    }
#pragma unroll
    for (int mi = 0; mi < 2; ++mi)
#pragma unroll
        for (int ni = 0; ni < 2; ++ni)
#pragma unroll
            for (int r = 0; r < 4; ++r) {
                int row = M0 + wr * 32 + mi * 16 + g * 4 + r;
                int col = N0 + wc * 32 + ni * 16 + li;
                C[(size_t)row * ldc + col] = acc[mi][ni][r];
            }
}

// ---------- fused RMSNorm + QKV write; q/k in fragment order ----------
__global__ __launch_bounds__(256) void rmsqkv_kernel(
    const float* __restrict__ wbuf,
    const float* __restrict__ g1, const float* __restrict__ g2, const float* __restrict__ g3,
    unsigned short* __restrict__ qbf, unsigned short* __restrict__ kbf,
    unsigned short* __restrict__ vb)
{
    const int d = threadIdx.x & 63;
    const int wv = threadIdx.x >> 6;
    const int ridx = blockIdx.x * 4 + wv;
    const int bt = ridx / HEADS;
    const int h = ridx % HEADS;
    const int b = bt >> 11, t = bt & (T_SEQ - 1);

    float v = wbuf[(size_t)bt * CDIM + h * DH + d];
    float ss = v * v;
#pragma unroll
    for (int m = 32; m; m >>= 1) ss += __shfl_xor(ss, m);
    float r = rsqrtf(ss * (1.0f / 64.0f) + RMS_EPS);
    float wn = v * r;

    const int bh = b * HEADS + h;
    // fragment-ordered index for (t, d)
    size_t fidx = (size_t)bh * (T_SEQ * DH)
                + (size_t)(t >> 7) * 8192
                + (size_t)((((t & 127) >> 4) * 2 + (d >> 5)) * 512
                           + ((d >> 3) & 3) * 128 + (t & 15) * 8 + (d & 7));
    qbf[fidx] = f2bf(wn * g1[d] * QSCALE);
    kbf[fidx] = f2bf(wn * g2[d]);
    vb[((size_t)bh * T_SEQ + t) * DH + d] = f2bf(wn * g3[d]);
}

// ---------- v [bh][t][f] -> fragment-ordered V^T tiles ----------
__global__ __launch_bounds__(256) void vtrans_kernel(
    const unsigned short* __restrict__ vb, unsigned short* __restrict__ vTf)
{
    __shared__ unsigned short raw[128 * 72];   // row stride 72 shorts (144B, 16B-aligned)
    const int bh = blockIdx.y, jt = blockIdx.x;
    const int tid = threadIdx.x;
    const unsigned short* src = &vb[((size_t)bh * T_SEQ + jt * 128) * DH];
#pragma unroll
    for (int p = 0; p < 4; ++p) {
        int i16 = p * 256 + tid;
        int r = i16 >> 3, c8 = i16 & 7;
        *(u32x4*)&raw[r * 72 + c8 * 8] = *(const u32x4*)&src[r * 64 + c8 * 8];
    }
    __syncthreads();
    unsigned short* dst = &vTf[(size_t)bh * (T_SEQ * DH) + (size_t)jt * 8192];
#pragma unroll
    for (int p = 0; p < 4; ++p) {
        int c = p * 256 + tid;
        int li = c & 15, g = (c >> 4) & 3, ni = (c >> 6) & 3, ks2 = c >> 8;
        int f = ni * 16 + li;
        int j0 = ks2 * 32 + g * 8;
        u32x4 out;
#pragma unroll
        for (int k = 0; k < 4; ++k) {
            unsigned int lo = raw[(j0 + 2 * k) * 72 + f];
            unsigned int hi = raw[(j0 + 2 * k + 1) * 72 + f];
            out[k] = lo | (hi << 16);
        }
        *(u32x4*)&dst[c * 8] = out;
    }
}

// ---------- pass 1: row/col sums of E = 2^(Q'K^T) --------------------------
// 1-D grid 1536, XCD-swizzled: each XCD owns 3 whole bh (Q/K panels resident).
// Wave w owns j rows w*32..+32 (K frags in regs). sQ double-buffered linear.
__global__ __launch_bounds__(256) void sums_kernel(
    const unsigned short* __restrict__ qbf, const unsigned short* __restrict__ kbf,
    float* __restrict__ rowsum, float* __restrict__ colsum)
{
    __shared__ unsigned short sQ[2][8192];
    const int tid = threadIdx.x;
    const int lane = tid & 63;
    const int w = tid >> 6;
    const int li = lane & 15;
    const int g = lane >> 4;

    const int wgid = blockIdx.x;
    const int xcd = wgid & 7;
    const int idx = wgid >> 3;                  // 0..191
    const int bh = xcd * 3 + (idx >> 6);        // 24 bh, 3 per XCD
    const int w2 = idx & 63;
    const int jx = w2 & 15;                     // 16 j-tiles
    const int iy = w2 >> 4;                     // 4 i-chunks
    const int J0 = jx * 128;

    const unsigned short* ktile = kbf + (size_t)bh * (T_SEQ * DH) + (size_t)jx * 8192;
    bf16x8 kf[2][2];
#pragma unroll
    for (int jb = 0; jb < 2; ++jb)
#pragma unroll
        for (int ks = 0; ks < 2; ++ks)
            kf[jb][ks] = *(const bf16x8*)&ktile[(size_t)((((w * 2 + jb) * 2 + ks) * 64 + lane) * 8)];

    const unsigned short* qbase = qbf + (size_t)bh * (T_SEQ * DH) + (size_t)(iy * 4) * 8192;
    stageLin(qbase, sQ[0], tid);
    __syncthreads();

    float csum[2][4];
#pragma unroll
    for (int jb = 0; jb < 2; ++jb)
#pragma unroll
        for (int r = 0; r < 4; ++r) csum[jb][r] = 0.0f;

    for (int it = 0; it < 4; ++it) {
        const int I0 = iy * 512 + it * 128;
        if (it + 1 < 4)
            stageLin(qbase + (size_t)(it + 1) * 8192, sQ[(it + 1) & 1], tid);
        const unsigned short* q = sQ[it & 1];

#pragma unroll
        for (int half = 0; half < 2; ++half) {
            f32x4 acc[2][4];
#pragma unroll
            for (int jb = 0; jb < 2; ++jb)
#pragma unroll
                for (int ib = 0; ib < 4; ++ib) acc[jb][ib] = (f32x4)0.0f;
#pragma unroll
            for (int ks = 0; ks < 2; ++ks) {
#pragma unroll
                for (int ib = 0; ib < 4; ++ib) {
                    bf16x8 qf = *(const bf16x8*)&q[(((half * 4 + ib) * 2 + ks) * 64 + lane) * 8];
#pragma unroll
                    for (int jb = 0; jb < 2; ++jb)
                        acc[jb][ib] = __builtin_amdgcn_mfma_f32_16x16x32_bf16(kf[jb][ks], qf, acc[jb][ib], 0, 0, 0);
                }
            }
#pragma unroll
            for (int ib = 0; ib < 4; ++ib) {
                float rp = 0.0f;
#pragma unroll
                for (int jb = 0; jb < 2; ++jb)
#pragma unroll
                    for (int r = 0; r < 4; ++r) {
                        float e = fast_exp2(acc[jb][ib][r]);
                        csum[jb][r] += e;
                        rp += e;
                    }
                rp += __shfl_xor(rp, 16);
                rp += __shfl_xor(rp, 32);      // sum over this wave's 32 j
                if (g == 0)
                    atomicAdd(&rowsum[(size_t)bh * T_SEQ + I0 + half * 64 + ib * 16 + li], rp);
            }
        }
        __syncthreads();   // drains next-tile stage (hidden under compute)
    }
#pragma unroll
    for (int jb = 0; jb < 2; ++jb)
#pragma unroll
        for (int r = 0; r < 4; ++r) {
            float c = csum[jb][r];
            c += __shfl_xor(c, 1); c += __shfl_xor(c, 2);
            c += __shfl_xor(c, 4); c += __shfl_xor(c, 8);
            if (li == 0)
                atomicAdd(&colsum[(size_t)bh * T_SEQ + J0 + w * 32 + jb * 16 + g * 4 + r], c);
        }
}

// ---------- in-place reciprocal over rowsum||colsum (vectorized) ----------
__global__ __launch_bounds__(256) void inv_kernel(float* __restrict__ s, int n4)
{
    int i = blockIdx.x * 256 + threadIdx.x;
    if (i < n4) {
        f32x4 v = ((f32x4*)s)[i];
        v[0] = fast_rcp(v[0]); v[1] = fast_rcp(v[1]);
        v[2] = fast_rcp(v[2]); v[3] = fast_rcp(v[3]);
        ((f32x4*)s)[i] = v;
    }
}

// ---------- pass 2: swapped QK^T + scale + PV; KVBLK=64, single-buffered ---
// 1-D grid 768, XCD-swizzled (3 bh per XCD). 24KB LDS -> 6 blocks/CU.
// T14 schedule, 64-j tiles (32 iters):
// { QKT(sK); pack->sP; sync(a); stageK(t+1); PV(sP,sV); sync(b); stageV(t+1) }
// rowinv/colinv are precomputed reciprocals (no rcp in the hot loop).
__global__ __launch_bounds__(256) void fused_pv_kernel(
    const unsigned short* __restrict__ qbf, const unsigned short* __restrict__ kbf,
    const unsigned short* __restrict__ vTf,
    const float* __restrict__ rowinv, const float* __restrict__ colinv,
    unsigned short* __restrict__ yh)
{
    __shared__ unsigned short sK[4096];      // 8 KB (64 j-rows)
    __shared__ unsigned short sV[4096];      // 8 KB
    __shared__ unsigned short sP[4096];      // 8 KB; 2KB wave-private regions

    const int tid = threadIdx.x;
    const int lane = tid & 63;
    const int w = tid >> 6;
    const int li = lane & 15;
    const int g = lane >> 4;

    const int wgid = blockIdx.x;
    const int xcd = wgid & 7;
    const int idx = wgid >> 3;                 // 0..95
    const int bh = xcd * 3 + (idx >> 5);       // 24 bh, 3 per XCD
    const int it = idx & 31;                   // 32 i-tiles
    const int I0 = it * 64;
    constexpr int NT = T_SEQ / 64;             // 32

    // Q fragments (coalesced 1KB wave loads from fragment-ordered global)
    const int rbq = ((I0 & 127) >> 4) + w;
    const unsigned short* qtile = qbf + (size_t)bh * (T_SEQ * DH) + (size_t)(I0 >> 7) * 8192;
    bf16x8 qf[2];
#pragma unroll
    for (int ks = 0; ks < 2; ++ks)
        qf[ks] = *(const bf16x8*)&qtile[(size_t)(((rbq * 2 + ks) * 64 + lane) * 8)];
    const float rv = rowinv[bh * T_SEQ + I0 + w * 16 + li];

    char* const sPw = (char*)sP + w * 2048;   // this wave's 2KB P region

    f32x4 accy[4];
#pragma unroll
    for (int i = 0; i < 4; ++i) accy[i] = (f32x4)0.0f;

    const size_t bhbase = (size_t)bh * (T_SEQ * DH);
    const unsigned short* kt0 = kbf + bhbase;   // 64-j subtile t at offset t*4096
    const unsigned short* vt0 = vTf + bhbase;

    // prologue: stage K(0), V(0)
    stage8k(kt0, sK, tid);
    stage8k(vt0, sV, tid);
    __syncthreads();

    for (int jt = 0; jt < NT; ++jt) {
        // --- QK^T (swapped: rows = j, cols = i) from sK ---
        f32x4 accs[4];
#pragma unroll
        for (int jb = 0; jb < 4; ++jb) accs[jb] = (f32x4)0.0f;
#pragma unroll
        for (int ks = 0; ks < 2; ++ks) {
#pragma unroll
            for (int jb = 0; jb < 4; ++jb) {
                bf16x8 kfr = *(const bf16x8*)&sK[((jb * 2 + ks) * 64 + lane) * 8];
                accs[jb] = __builtin_amdgcn_mfma_f32_16x16x32_bf16(kfr, qf[ks], accs[jb], 0, 0, 0);
            }
        }

        // --- pack: P = 2^S' * (rinv_i + cinv_j) -> bf16 -> sP (own region) ---
#pragma unroll
        for (int jb = 0; jb < 4; ++jb) {
            f32x4 cv = *(const f32x4*)&colinv[(size_t)bh * T_SEQ + jt * 64 + jb * 16 + g * 4];
            float p0 = fast_exp2(accs[jb][0]) * (rv + cv[0]);
            float p1 = fast_exp2(accs[jb][1]) * (rv + cv[1]);
            float p2 = fast_exp2(accs[jb][2]) * (rv + cv[2]);
            float p3 = fast_exp2(accs[jb][3]) * (rv + cv[3]);
            uint2 pw;
            pw.x = cvt_pk_bf16(p0, p1);
            pw.y = cvt_pk_bf16(p2, p3);
            int off = ((jb >> 1) * 4 + (jb & 1) * 2 + (g >> 1)) * 256 + li * 16 + (g & 1) * 8;
            *(uint2*)(sPw + off) = pw;
        }

        __syncthreads();   // (a): sK reads done; drains V(jt) stage from prev (b)
        if (jt + 1 < NT)
            stage8k(kt0 + (size_t)(jt + 1) * 4096, sK, tid);

        // --- PV: y[i][f] += P[i][j] * V^T[f][j] from sP / sV ---
#pragma unroll
        for (int ks2 = 0; ks2 < 2; ++ks2) {
            bf16x8 pf = *(const bf16x8*)(sPw + ((ks2 * 4 + g) * 256 + li * 16));
#pragma unroll
            for (int ni = 0; ni < 4; ++ni) {
                bf16x8 vf = *(const bf16x8*)&sV[(ks2 * 256 + ni * 64 + lane) * 8];
                accy[ni] = __builtin_amdgcn_mfma_f32_16x16x32_bf16(pf, vf, accy[ni], 0, 0, 0);
            }
        }

        __syncthreads();   // (b): sV reads done; drains K(jt+1) stage
        if (jt + 1 < NT)
            stage8k(vt0 + (size_t)(jt + 1) * 4096, sV, tid);
    }

    // write final bf16 y at [b, i, h*64+f]
    const int b_ = bh / HEADS, h = bh % HEADS;
#pragma unroll
    for (int ni = 0; ni < 4; ++ni)
#pragma unroll
        for (int r = 0; r < 4; ++r) {
            int i = I0 + w * 16 + g * 4 + r;
            int col = h * DH + ni * 16 + li;
            yh[((size_t)b_ * T_SEQ + i) * CDIM + col] = f2bf(accy[ni][r]);
        }
}

// ---------- host ----------
extern "C" void kernel_launch(void* const* d_in, const int* in_sizes, int n_in,
                              void* d_out, int out_size, void* d_ws, size_t ws_size,
                              hipStream_t stream)
{
    const float* x  = (const float*)d_in[0];
    const float* W  = (const float*)d_in[1];
    const float* g1 = (const float*)d_in[2];
    const float* g2 = (const float*)d_in[3];
    const float* g3 = (const float*)d_in[4];
    float* out = (float*)d_out;

    char* p = (char*)d_ws;
    auto alloc = [&](size_t bytes) -> void* {
        void* r = (void*)p;
        p += (bytes + 255) & ~(size_t)255;
        return r;
    };
    const size_t NC  = (size_t)NROWS * CDIM;
    const size_t WSZ = (size_t)CDIM * CDIM;
    const size_t QSZ = (size_t)BH_TOT * T_SEQ * DH;

    unsigned short* xh   = (unsigned short*)alloc(NC * 2);
    unsigned short* Wh   = (unsigned short*)alloc(WSZ * 2);
    unsigned short* WTh  = (unsigned short*)alloc(WSZ * 2);
    float*          wbuf = (float*)alloc(NC * 4);
    unsigned short* qbf  = (unsigned short*)alloc(QSZ * 2);
    unsigned short* kbf  = (unsigned short*)alloc(QSZ * 2);
    unsigned short* vb   = (unsigned short*)alloc(QSZ * 2);
    unsigned short* vTf  = (unsigned short*)alloc(QSZ * 2);
    unsigned short* yh   = (unsigned short*)alloc(NC * 2);
    // rowsum || colsum contiguous: one memset + one in-place inv cover both
    float* rowsum = (float*)alloc((size_t)BH_TOT * T_SEQ * 4 * 2);
    float* colsum = rowsum + (size_t)BH_TOT * T_SEQ;

    prep_kernel<<<2048, 256, 0, stream>>>(x, W, xh, Wh, WTh);
    gemm64_nt<<<(NROWS / 64) * (CDIM / 64), 256, 0, stream>>>(
        xh, Wh, wbuf, NROWS, CDIM, CDIM, CDIM);
    rmsqkv_kernel<<<(NROWS * HEADS) / 4, 256, 0, stream>>>(
        wbuf, g1, g2, g3, qbf, kbf, vb);
    vtrans_kernel<<<dim3(T_SEQ / 128, BH_TOT), 256, 0, stream>>>(vb, vTf);

    hipMemsetAsync(rowsum, 0, (size_t)BH_TOT * T_SEQ * 4 * 2, stream);
    sums_kernel<<<(T_SEQ / 128) * 4 * BH_TOT, 256, 0, stream>>>(
        qbf, kbf, rowsum, colsum);
    {
        int n4 = BH_TOT * T_SEQ * 2 / 4;
        inv_kernel<<<(n4 + 255) / 256, 256, 0, stream>>>(rowsum, n4);
    }

    fused_pv_kernel<<<(T_SEQ / 64) * BH_TOT, 256, 0, stream>>>(
        qbf, kbf, vTf, rowsum, colsum, yh);

    gemm64_nt<<<(NROWS / 64) * (CDIM / 64), 256, 0, stream>>>(
        yh, WTh, out, NROWS, CDIM, CDIM, CDIM);
}